// Round 4
// baseline (2687.727 us; speedup 1.0000x reference)
//
#include <hip/hip_runtime.h>
#include <hip/hip_bf16.h>

typedef short short8 __attribute__((ext_vector_type(8)));
typedef float f32x4 __attribute__((ext_vector_type(4)));
typedef unsigned short u16;

#define BM 64
#define BN 64
#define BK 32
#define KST 40  // padded LDS k-stride (elements); 40*2B = 80B, 16B-aligned rows

// fp32 -> bf16 round-to-nearest-even (payload as u16)
static __device__ __forceinline__ u16 f2b(float f) {
  union { float f; unsigned u; } x; x.f = f;
  unsigned r = x.u + 0x7FFF + ((x.u >> 16) & 1);
  return (u16)(r >> 16);
}
static __device__ __forceinline__ float b2f(u16 u) {
  unsigned int x = ((unsigned int)u) << 16;
  float f; __builtin_memcpy(&f, &x, 4);
  return f;
}

// Load 8 consecutive elements as bf16 payloads.
static __device__ __forceinline__ void load8(const u16* p, u16* dst) {
  union { uint4 u; u16 h[8]; } t;
  t.u = *(const uint4*)p;
  #pragma unroll
  for (int j = 0; j < 8; ++j) dst[j] = t.h[j];
}
static __device__ __forceinline__ void load8(const float* p, u16* dst) {
  float4 a = ((const float4*)p)[0];
  float4 b = ((const float4*)p)[1];
  dst[0] = f2b(a.x); dst[1] = f2b(a.y); dst[2] = f2b(a.z); dst[3] = f2b(a.w);
  dst[4] = f2b(b.x); dst[5] = f2b(b.y); dst[6] = f2b(b.z); dst[7] = f2b(b.w);
}

// ---------------------------------------------------------------------------
// Mixed-dtype GEMM: C = (A @ B) * alpha + bias   (bf16 MFMA, fp32 accum)
//  TyA/TyB: float (converted at staging) or u16 (bf16 payload)
//  TA: A stored [K][M] (row stride lda); TB: B stored [N][K] (row stride ldb)
//  grid: (N/BN, M/BM); block: 256 threads (4 waves)
// MFMA 16x16x32 bf16 verified layouts (guide §3, m89/m91):
//   A-frag: lane holds A[m=lane&15][k=(lane>>4)*8+j]
//   B-frag: lane holds B[k=(lane>>4)*8+j][n=lane&15]
//   C/D   : lane reg r holds D[row=(lane>>4)*4+r][col=lane&15]
// ---------------------------------------------------------------------------
template<typename TyA, typename TyB, bool TA, bool TB, typename OutT>
__global__ __launch_bounds__(256) void gemm_kernel(
    const TyA* __restrict__ A, const TyB* __restrict__ B,
    const float* __restrict__ bias, const float* __restrict__ alpha_ptr,
    OutT* __restrict__ C, int K, int lda, int ldb, int ldc)
{
  __shared__ u16 As[BM * KST];  // [m][k] (k contiguous)
  __shared__ u16 Bs[BN * KST];  // [n][k] (k contiguous)

  const int tid = threadIdx.x;
  const int m0 = blockIdx.y * BM;
  const int n0 = blockIdx.x * BN;
  const int w    = tid >> 6;     // wave 0..3 -> m rows [w*16, w*16+16)
  const int lane = tid & 63;
  const int lrow = lane & 15;
  const int lk   = (lane >> 4) * 8;

  f32x4 acc[4] = {};

  for (int k0 = 0; k0 < K; k0 += BK) {
    union { uint4 u; u16 h[8]; } t;
    if (!TA) {  // A row-major [M][K]
      const int r = tid >> 2, c = (tid & 3) * 8;
      load8(A + (long long)(m0 + r) * lda + (k0 + c), t.h);
      *(uint4*)(As + r * KST + c) = t.u;
    } else {    // A stored [K][M]
      const int kk = tid >> 3, mm = (tid & 7) * 8;
      load8(A + (long long)(k0 + kk) * lda + (m0 + mm), t.h);
      #pragma unroll
      for (int j = 0; j < 8; ++j) As[(mm + j) * KST + kk] = t.h[j];
    }
    if (!TB) {  // B row-major [K][N]
      const int kk = tid >> 3, nn = (tid & 7) * 8;
      load8(B + (long long)(k0 + kk) * ldb + (n0 + nn), t.h);
      #pragma unroll
      for (int j = 0; j < 8; ++j) Bs[(nn + j) * KST + kk] = t.h[j];
    } else {    // B stored [N][K]
      const int nn = tid >> 2, kk = (tid & 3) * 8;
      load8(B + (long long)(n0 + nn) * ldb + (k0 + kk), t.h);
      *(uint4*)(Bs + nn * KST + kk) = t.u;
    }
    __syncthreads();

    short8 a = *(const short8*)(As + (w * 16 + lrow) * KST + lk);
    #pragma unroll
    for (int i = 0; i < 4; ++i) {
      short8 b = *(const short8*)(Bs + (i * 16 + lrow) * KST + lk);
      acc[i] = __builtin_amdgcn_mfma_f32_16x16x32_bf16(a, b, acc[i], 0, 0, 0);
    }
    __syncthreads();
  }

  const float alpha = alpha_ptr ? *alpha_ptr : 1.0f;
  #pragma unroll
  for (int i = 0; i < 4; ++i) {
    const int n = n0 + i * 16 + lrow;
    const float bv = bias ? bias[n] : 0.0f;
    #pragma unroll
    for (int r = 0; r < 4; ++r) {
      const int m = m0 + w * 16 + (lane >> 4) * 4 + r;
      C[(long long)m * ldc + n] = OutT(acc[i][r] * alpha + bv);
    }
  }
}

// ---------------------------------------------------------------------------
// LayerNorm + ReLU over rows of 768 fp32 -> OutT. ReLU propagates NaN.
//  OutT = __hip_bfloat16 (intermediates) or float (final output buffer).
// ---------------------------------------------------------------------------
template<typename OutT>
__global__ __launch_bounds__(256) void ln_relu_kernel(
    const float* __restrict__ x, const float* __restrict__ g,
    const float* __restrict__ beta, OutT* __restrict__ out)
{
  __shared__ float sa[4], sb[4];
  const float* xr = x + (long long)blockIdx.x * 768;
  float v[3]; float s = 0.f, ss = 0.f;
  #pragma unroll
  for (int j = 0; j < 3; ++j) {
    v[j] = xr[threadIdx.x + j * 256];
    s += v[j]; ss += v[j] * v[j];
  }
  #pragma unroll
  for (int off = 32; off; off >>= 1) {
    s  += __shfl_down(s, off);
    ss += __shfl_down(ss, off);
  }
  const int w = threadIdx.x >> 6, lane = threadIdx.x & 63;
  if (!lane) { sa[w] = s; sb[w] = ss; }
  __syncthreads();
  s  = sa[0] + sa[1] + sa[2] + sa[3];
  ss = sb[0] + sb[1] + sb[2] + sb[3];
  const float mean = s * (1.f / 768.f);
  const float var  = ss * (1.f / 768.f) - mean * mean;
  const float rst  = rsqrtf(var + 1e-5f);
  OutT* orow = out + (long long)blockIdx.x * 768;
  #pragma unroll
  for (int j = 0; j < 3; ++j) {
    const int idx = threadIdx.x + j * 256;
    const float yv = (v[j] - mean) * rst * g[idx] + beta[idx];
    const float rv = (yv <= 0.f) ? 0.f : yv;  // NaN -> yv (propagates)
    orow[idx] = OutT(rv);
  }
}

// ---------------------------------------------------------------------------
// In-place row softmax over 2048 bf16 values (fp32 math)
// ---------------------------------------------------------------------------
__global__ __launch_bounds__(256) void softmax_kernel(u16* __restrict__ sim)
{
  __shared__ float sm[4], ssum[4];
  u16* row = sim + (long long)blockIdx.x * 2048;
  union { uint4 u; u16 h[8]; } v;
  v.u = *(const uint4*)(row + threadIdx.x * 8);
  float f[8]; float mx = -1e30f;
  #pragma unroll
  for (int j = 0; j < 8; ++j) { f[j] = b2f(v.h[j]); mx = fmaxf(mx, f[j]); }
  #pragma unroll
  for (int off = 32; off; off >>= 1) mx = fmaxf(mx, __shfl_down(mx, off));
  const int w = threadIdx.x >> 6, lane = threadIdx.x & 63;
  if (!lane) sm[w] = mx;
  __syncthreads();
  mx = fmaxf(fmaxf(sm[0], sm[1]), fmaxf(sm[2], sm[3]));
  float s = 0.f;
  #pragma unroll
  for (int j = 0; j < 8; ++j) { f[j] = __expf(f[j] - mx); s += f[j]; }
  #pragma unroll
  for (int off = 32; off; off >>= 1) s += __shfl_down(s, off);
  if (!lane) ssum[w] = s;
  __syncthreads();
  s = ssum[0] + ssum[1] + ssum[2] + ssum[3];
  const float inv = 1.f / s;
  #pragma unroll
  for (int j = 0; j < 8; ++j) v.h[j] = f2b(f[j] * inv);
  *(uint4*)(row + threadIdx.x * 8) = v.u;
}

// ---------------------------------------------------------------------------
// scale = mean(claw) / 0.07  (single block, fp32 input)
// ---------------------------------------------------------------------------
__global__ __launch_bounds__(256) void claw_mean_kernel(
    const float* __restrict__ claw, float* __restrict__ scale, int n)
{
  __shared__ float sa[4];
  float s = 0.f;
  const int nv = n >> 2;
  for (int i = threadIdx.x; i < nv; i += 256) {
    float4 v = ((const float4*)claw)[i];
    s += v.x + v.y + v.z + v.w;
  }
  #pragma unroll
  for (int off = 32; off; off >>= 1) s += __shfl_down(s, off);
  const int w = threadIdx.x >> 6, lane = threadIdx.x & 63;
  if (!lane) sa[w] = s;
  __syncthreads();
  if (threadIdx.x == 0) {
    const float t = sa[0] + sa[1] + sa[2] + sa[3];
    *scale = t / ((float)n * 0.07f);
  }
}

// ---------------------------------------------------------------------------
extern "C" void kernel_launch(void* const* d_in, const int* in_sizes, int n_in,
                              void* d_out, int out_size, void* d_ws, size_t ws_size,
                              hipStream_t stream)
{
  // Reference setup_inputs(): ALL tensors float32; reference OUTPUT is float32.
  const float* vis   = (const float*)d_in[0];
  const float* lang  = (const float*)d_in[1];
  const float* vW    = (const float*)d_in[2];
  const float* vb    = (const float*)d_in[3];
  const float* vg    = (const float*)d_in[4];
  const float* vbeta = (const float*)d_in[5];
  const float* lW    = (const float*)d_in[6];
  const float* lb    = (const float*)d_in[7];
  const float* lg    = (const float*)d_in[8];
  const float* lbeta = (const float*)d_in[9];
  const float* claw  = (const float*)d_in[10];
  const float* oW    = (const float*)d_in[11];
  const float* ob    = (const float*)d_in[12];
  const float* og    = (const float*)d_in[13];
  const float* obeta = (const float*)d_in[14];
  float* out = (float*)d_out;  // fp32 output buffer

  constexpr int NB = 8, S = 2048, D = 768;

  // Per-batch workspace (reused across the 8 batches). Total: 27,262,980 B.
  char* ws = (char*)d_ws;
  u16*   vp    = (u16*)  (ws);             //  3,145,728  bf16 [S][D]
  u16*   lp    = (u16*)  (ws +  3145728);  //  3,145,728  bf16 [S][D]
  u16*   comb  = (u16*)  (ws +  6291456);  //  6,291,456  bf16 [S][2D]
  u16*   sim   = (u16*)  (ws + 12582912);  //  8,388,608  bf16 [S][S]
  float* y     = (float*)(ws + 20971520);  //  6,291,456  fp32 [S][D]
  float* scale = (float*)(ws + 27262976);  //  4

  const dim3 blk(256);

  claw_mean_kernel<<<1, blk, 0, stream>>>(claw, scale, in_sizes[10]);

  for (int b = 0; b < NB; ++b) {
    const float* vis_b  = vis  + (long long)b * S * D;
    const float* lang_b = lang + (long long)b * S * D;
    float* out_b = out + (long long)b * S * D;

    // vision projection: y = vis_b @ vW + vb ; vp = relu(LN(y))
    gemm_kernel<float, float, false, false, float>
        <<<dim3(D / BN, S / BM), blk, 0, stream>>>(
        vis_b, vW, vb, nullptr, y, D, D, D, D);
    ln_relu_kernel<__hip_bfloat16><<<S, blk, 0, stream>>>(
        y, vg, vbeta, (__hip_bfloat16*)vp);

    // language projection
    gemm_kernel<float, float, false, false, float>
        <<<dim3(D / BN, S / BM), blk, 0, stream>>>(
        lang_b, lW, lb, nullptr, y, D, D, D, D);
    ln_relu_kernel<__hip_bfloat16><<<S, blk, 0, stream>>>(
        y, lg, lbeta, (__hip_bfloat16*)lp);

    // sim = (vp @ lp^T) * scale ; A = softmax(sim) in place
    gemm_kernel<u16, u16, false, true, __hip_bfloat16>
        <<<dim3(S / BN, S / BM), blk, 0, stream>>>(
        vp, lp, nullptr, scale, (__hip_bfloat16*)sim, D, D, D, S);
    softmax_kernel<<<S, blk, 0, stream>>>(sim);

    // aligned_vision = A @ vp -> comb[:, 0:768]
    gemm_kernel<u16, u16, false, false, __hip_bfloat16>
        <<<dim3(D / BN, S / BM), blk, 0, stream>>>(
        sim, vp, nullptr, nullptr, (__hip_bfloat16*)comb, S, S, D, 2 * D);
    // aligned_language = A^T @ lp -> comb[:, 768:1536]
    gemm_kernel<u16, u16, true, false, __hip_bfloat16>
        <<<dim3(D / BN, S / BM), blk, 0, stream>>>(
        sim, lp, nullptr, nullptr, (__hip_bfloat16*)comb + D, S, S, D, 2 * D);

    // out_b = relu(LN(comb @ oW + ob))  -- final LN writes fp32 to d_out
    gemm_kernel<u16, float, false, false, float>
        <<<dim3(D / BN, S / BM), blk, 0, stream>>>(
        comb, oW, ob, nullptr, y, 2 * D, 2 * D, D, D);
    ln_relu_kernel<float><<<S, blk, 0, stream>>>(y, og, obeta, out_b);
  }
}

// Round 5
// 1379.393 us; speedup vs baseline: 1.9485x; 1.9485x over previous
//
#include <hip/hip_runtime.h>
#include <hip/hip_bf16.h>

typedef short short8 __attribute__((ext_vector_type(8)));
typedef float f32x4 __attribute__((ext_vector_type(4)));
typedef unsigned short u16;

#define BM 64
#define BN 64
#define BK 32
#define KST 40  // padded LDS k-stride (elements); 40*2B = 80B, 16B-aligned rows

// fp32 -> bf16 round-to-nearest-even (payload as u16)
static __device__ __forceinline__ u16 f2b(float f) {
  union { float f; unsigned u; } x; x.f = f;
  unsigned r = x.u + 0x7FFF + ((x.u >> 16) & 1);
  return (u16)(r >> 16);
}
static __device__ __forceinline__ float b2f(u16 u) {
  unsigned int x = ((unsigned int)u) << 16;
  float f; __builtin_memcpy(&f, &x, 4);
  return f;
}

// Load 8 consecutive elements as bf16 payloads.
static __device__ __forceinline__ void load8(const u16* p, u16* dst) {
  union { uint4 u; u16 h[8]; } t;
  t.u = *(const uint4*)p;
  #pragma unroll
  for (int j = 0; j < 8; ++j) dst[j] = t.h[j];
}
static __device__ __forceinline__ void load8(const float* p, u16* dst) {
  float4 a = ((const float4*)p)[0];
  float4 b = ((const float4*)p)[1];
  dst[0] = f2b(a.x); dst[1] = f2b(a.y); dst[2] = f2b(a.z); dst[3] = f2b(a.w);
  dst[4] = f2b(b.x); dst[5] = f2b(b.y); dst[6] = f2b(b.z); dst[7] = f2b(b.w);
}

// ---------------------------------------------------------------------------
// Mixed-dtype batched GEMM: C[z] = (A[z] @ B[z]) * alpha + bias
//  TyA/TyB: float (converted at staging) or u16 (bf16 payload)
//  TA: A stored [K][M] (row stride lda); TB: B stored [N][K] (row stride ldb)
//  grid: (N/BN, M/BM, batch); block: 256 threads (4 waves)
// MFMA 16x16x32 bf16 verified layouts (guide §3, m89/m91):
//   A-frag: lane holds A[m=lane&15][k=(lane>>4)*8+j]
//   B-frag: lane holds B[k=(lane>>4)*8+j][n=lane&15]
//   C/D   : lane reg r holds D[row=(lane>>4)*4+r][col=lane&15]
// ---------------------------------------------------------------------------
template<typename TyA, typename TyB, bool TA, bool TB, typename OutT>
__global__ __launch_bounds__(256) void gemm_kernel(
    const TyA* __restrict__ A, const TyB* __restrict__ B,
    const float* __restrict__ bias, const float* __restrict__ alpha_ptr,
    OutT* __restrict__ C, int K, int lda, int ldb, int ldc,
    long long sA, long long sB, long long sC)
{
  __shared__ u16 As[BM * KST];  // [m][k] (k contiguous)
  __shared__ u16 Bs[BN * KST];  // [n][k] (k contiguous)

  A += (long long)blockIdx.z * sA;
  B += (long long)blockIdx.z * sB;
  C += (long long)blockIdx.z * sC;

  const int tid = threadIdx.x;
  const int m0 = blockIdx.y * BM;
  const int n0 = blockIdx.x * BN;
  const int w    = tid >> 6;     // wave 0..3 -> m rows [w*16, w*16+16)
  const int lane = tid & 63;
  const int lrow = lane & 15;
  const int lk   = (lane >> 4) * 8;

  f32x4 acc[4] = {};

  for (int k0 = 0; k0 < K; k0 += BK) {
    union { uint4 u; u16 h[8]; } t;
    if (!TA) {  // A row-major [M][K]
      const int r = tid >> 2, c = (tid & 3) * 8;
      load8(A + (long long)(m0 + r) * lda + (k0 + c), t.h);
      *(uint4*)(As + r * KST + c) = t.u;
    } else {    // A stored [K][M]
      const int kk = tid >> 3, mm = (tid & 7) * 8;
      load8(A + (long long)(k0 + kk) * lda + (m0 + mm), t.h);
      #pragma unroll
      for (int j = 0; j < 8; ++j) As[(mm + j) * KST + kk] = t.h[j];
    }
    if (!TB) {  // B row-major [K][N]
      const int kk = tid >> 3, nn = (tid & 7) * 8;
      load8(B + (long long)(k0 + kk) * ldb + (n0 + nn), t.h);
      #pragma unroll
      for (int j = 0; j < 8; ++j) Bs[(nn + j) * KST + kk] = t.h[j];
    } else {    // B stored [N][K]
      const int nn = tid >> 2, kk = (tid & 3) * 8;
      load8(B + (long long)(n0 + nn) * ldb + (k0 + kk), t.h);
      *(uint4*)(Bs + nn * KST + kk) = t.u;
    }
    __syncthreads();

    short8 a = *(const short8*)(As + (w * 16 + lrow) * KST + lk);
    #pragma unroll
    for (int i = 0; i < 4; ++i) {
      short8 b = *(const short8*)(Bs + (i * 16 + lrow) * KST + lk);
      acc[i] = __builtin_amdgcn_mfma_f32_16x16x32_bf16(a, b, acc[i], 0, 0, 0);
    }
    __syncthreads();
  }

  const float alpha = alpha_ptr ? *alpha_ptr : 1.0f;
  #pragma unroll
  for (int i = 0; i < 4; ++i) {
    const int n = n0 + i * 16 + lrow;
    const float bv = bias ? bias[n] : 0.0f;
    #pragma unroll
    for (int r = 0; r < 4; ++r) {
      const int m = m0 + w * 16 + (lane >> 4) * 4 + r;
      C[(long long)m * ldc + n] = OutT(acc[i][r] * alpha + bv);
    }
  }
}

// ---------------------------------------------------------------------------
// LayerNorm + ReLU over rows of 768 fp32 -> OutT. ReLU propagates NaN.
// ---------------------------------------------------------------------------
template<typename OutT>
__global__ __launch_bounds__(256) void ln_relu_kernel(
    const float* __restrict__ x, const float* __restrict__ g,
    const float* __restrict__ beta, OutT* __restrict__ out)
{
  __shared__ float sa[4], sb[4];
  const float* xr = x + (long long)blockIdx.x * 768;
  float v[3]; float s = 0.f, ss = 0.f;
  #pragma unroll
  for (int j = 0; j < 3; ++j) {
    v[j] = xr[threadIdx.x + j * 256];
    s += v[j]; ss += v[j] * v[j];
  }
  #pragma unroll
  for (int off = 32; off; off >>= 1) {
    s  += __shfl_down(s, off);
    ss += __shfl_down(ss, off);
  }
  const int w = threadIdx.x >> 6, lane = threadIdx.x & 63;
  if (!lane) { sa[w] = s; sb[w] = ss; }
  __syncthreads();
  s  = sa[0] + sa[1] + sa[2] + sa[3];
  ss = sb[0] + sb[1] + sb[2] + sb[3];
  const float mean = s * (1.f / 768.f);
  const float var  = ss * (1.f / 768.f) - mean * mean;
  const float rst  = rsqrtf(var + 1e-5f);
  OutT* orow = out + (long long)blockIdx.x * 768;
  #pragma unroll
  for (int j = 0; j < 3; ++j) {
    const int idx = threadIdx.x + j * 256;
    const float yv = (v[j] - mean) * rst * g[idx] + beta[idx];
    const float rv = (yv <= 0.f) ? 0.f : yv;  // NaN -> yv (propagates)
    orow[idx] = OutT(rv);
  }
}

// ---------------------------------------------------------------------------
// In-place row softmax over 2048 bf16 values (fp32 math)
// ---------------------------------------------------------------------------
__global__ __launch_bounds__(256) void softmax_kernel(u16* __restrict__ sim)
{
  __shared__ float sm[4], ssum[4];
  u16* row = sim + (long long)blockIdx.x * 2048;
  union { uint4 u; u16 h[8]; } v;
  v.u = *(const uint4*)(row + threadIdx.x * 8);
  float f[8]; float mx = -1e30f;
  #pragma unroll
  for (int j = 0; j < 8; ++j) { f[j] = b2f(v.h[j]); mx = fmaxf(mx, f[j]); }
  #pragma unroll
  for (int off = 32; off; off >>= 1) mx = fmaxf(mx, __shfl_down(mx, off));
  const int w = threadIdx.x >> 6, lane = threadIdx.x & 63;
  if (!lane) sm[w] = mx;
  __syncthreads();
  mx = fmaxf(fmaxf(sm[0], sm[1]), fmaxf(sm[2], sm[3]));
  float s = 0.f;
  #pragma unroll
  for (int j = 0; j < 8; ++j) { f[j] = __expf(f[j] - mx); s += f[j]; }
  #pragma unroll
  for (int off = 32; off; off >>= 1) s += __shfl_down(s, off);
  if (!lane) ssum[w] = s;
  __syncthreads();
  s = ssum[0] + ssum[1] + ssum[2] + ssum[3];
  const float inv = 1.f / s;
  #pragma unroll
  for (int j = 0; j < 8; ++j) v.h[j] = f2b(f[j] * inv);
  *(uint4*)(row + threadIdx.x * 8) = v.u;
}

// ---------------------------------------------------------------------------
// claw mean: stage 1 — 64 blocks write partial sums (deterministic)
// ---------------------------------------------------------------------------
__global__ __launch_bounds__(256) void claw_partial_kernel(
    const float* __restrict__ claw, float* __restrict__ partial, int n)
{
  __shared__ float sa[4];
  float s = 0.f;
  const int nv = n >> 2;
  for (int i = blockIdx.x * 256 + threadIdx.x; i < nv; i += 64 * 256) {
    float4 v = ((const float4*)claw)[i];
    s += v.x + v.y + v.z + v.w;
  }
  #pragma unroll
  for (int off = 32; off; off >>= 1) s += __shfl_down(s, off);
  const int w = threadIdx.x >> 6, lane = threadIdx.x & 63;
  if (!lane) sa[w] = s;
  __syncthreads();
  if (threadIdx.x == 0)
    partial[blockIdx.x] = sa[0] + sa[1] + sa[2] + sa[3];
}

// stage 2 — 1 block of 64 lanes: scale = (sum partial)/(n*T)
__global__ void claw_final_kernel(
    const float* __restrict__ partial, float* __restrict__ scale, float inv)
{
  float s = partial[threadIdx.x];
  #pragma unroll
  for (int off = 32; off; off >>= 1) s += __shfl_down(s, off);
  if (threadIdx.x == 0) *scale = s * inv;
}

// ---------------------------------------------------------------------------
extern "C" void kernel_launch(void* const* d_in, const int* in_sizes, int n_in,
                              void* d_out, int out_size, void* d_ws, size_t ws_size,
                              hipStream_t stream)
{
  // Reference setup_inputs(): ALL tensors float32; reference OUTPUT is float32.
  const float* vis   = (const float*)d_in[0];
  const float* lang  = (const float*)d_in[1];
  const float* vW    = (const float*)d_in[2];
  const float* vb    = (const float*)d_in[3];
  const float* vg    = (const float*)d_in[4];
  const float* vbeta = (const float*)d_in[5];
  const float* lW    = (const float*)d_in[6];
  const float* lb    = (const float*)d_in[7];
  const float* lg    = (const float*)d_in[8];
  const float* lbeta = (const float*)d_in[9];
  const float* claw  = (const float*)d_in[10];
  const float* oW    = (const float*)d_in[11];
  const float* ob    = (const float*)d_in[12];
  const float* og    = (const float*)d_in[13];
  const float* obeta = (const float*)d_in[14];
  float* out = (float*)d_out;

  constexpr int NB = 8, S = 2048, D = 768;
  constexpr long long SD = (long long)S * D;      // 1,572,864
  constexpr long long SS = (long long)S * S;      // 4,194,304
  const int nclaw = in_sizes[10];
  const float claw_inv = 1.0f / ((float)nclaw * 0.07f);
  const dim3 blk(256);

  // ---- full-batch workspace layout (167,772,432 B) ----
  //   vp   bf16 [R=16384][768]  @ 0           25,165,824
  //   lp   bf16 [R][768]        @ 25165824    25,165,824
  //   comb bf16 [R][1536]       @ 50331648    50,331,648
  //   sim  bf16 [8][2048][2048] @ 100663296   67,108,864  (aliases y:
  //   y    fp32 [R][768]        @ 100663296   50,331,648   y dead when sim
  //   scale fp32                @ 167772160                written & vice versa)
  //   partial fp32[64]          @ 167772176
  const size_t need_full = 167772432;

  char* ws = (char*)d_ws;
  if (ws_size >= need_full) {
    constexpr int R = NB * S;  // 16384
    u16*   vp      = (u16*)  (ws);
    u16*   lp      = (u16*)  (ws + 25165824);
    u16*   comb    = (u16*)  (ws + 50331648);
    u16*   sim     = (u16*)  (ws + 100663296);
    float* y       = (float*)(ws + 100663296);
    float* scale   = (float*)(ws + 167772160);
    float* partial = (float*)(ws + 167772176);

    claw_partial_kernel<<<64, blk, 0, stream>>>(claw, partial, nclaw);
    claw_final_kernel<<<1, 64, 0, stream>>>(partial, scale, claw_inv);

    // vision projection over all 16384 rows
    gemm_kernel<float, float, false, false, float>
        <<<dim3(D / BN, R / BM, 1), blk, 0, stream>>>(
        vis, vW, vb, nullptr, y, D, D, D, D, 0, 0, 0);
    ln_relu_kernel<__hip_bfloat16><<<R, blk, 0, stream>>>(
        y, vg, vbeta, (__hip_bfloat16*)vp);

    // language projection
    gemm_kernel<float, float, false, false, float>
        <<<dim3(D / BN, R / BM, 1), blk, 0, stream>>>(
        lang, lW, lb, nullptr, y, D, D, D, D, 0, 0, 0);
    ln_relu_kernel<__hip_bfloat16><<<R, blk, 0, stream>>>(
        y, lg, lbeta, (__hip_bfloat16*)lp);

    // sim[z] = (vp[z] @ lp[z]^T) * scale ; softmax rows in place
    gemm_kernel<u16, u16, false, true, __hip_bfloat16>
        <<<dim3(S / BN, S / BM, NB), blk, 0, stream>>>(
        vp, lp, nullptr, scale, (__hip_bfloat16*)sim, D, D, D, S, SD, SD, SS);
    softmax_kernel<<<R, blk, 0, stream>>>(sim);

    // aligned_vision[z] = A[z] @ vp[z] -> comb[:, 0:768]
    gemm_kernel<u16, u16, false, false, __hip_bfloat16>
        <<<dim3(D / BN, S / BM, NB), blk, 0, stream>>>(
        sim, vp, nullptr, nullptr, (__hip_bfloat16*)comb,
        S, S, D, 2 * D, SS, SD, 2 * SD);
    // aligned_language[z] = A[z]^T @ lp[z] -> comb[:, 768:1536]
    gemm_kernel<u16, u16, true, false, __hip_bfloat16>
        <<<dim3(D / BN, S / BM, NB), blk, 0, stream>>>(
        sim, lp, nullptr, nullptr, (__hip_bfloat16*)comb + D,
        S, S, D, 2 * D, SS, SD, 2 * SD);

    // out = relu(LN(comb @ oW + ob))   (final GEMM writes y over dead sim)
    gemm_kernel<u16, float, false, false, float>
        <<<dim3(D / BN, R / BM, 1), blk, 0, stream>>>(
        comb, oW, ob, nullptr, y, 2 * D, 2 * D, D, D, 0, 0, 0);
    ln_relu_kernel<float><<<R, blk, 0, stream>>>(y, og, obeta, out);
    return;
  }

  // ---- fallback: per-batch loop, 27.3 MB workspace (round-4 proven path) ----
  u16*   vp      = (u16*)  (ws);
  u16*   lp      = (u16*)  (ws +  3145728);
  u16*   comb    = (u16*)  (ws +  6291456);
  u16*   sim     = (u16*)  (ws + 12582912);
  float* y       = (float*)(ws + 20971520);
  float* scale   = (float*)(ws + 27262976);
  float* partial = (float*)(ws + 27262992);

  claw_partial_kernel<<<64, blk, 0, stream>>>(claw, partial, nclaw);
  claw_final_kernel<<<1, 64, 0, stream>>>(partial, scale, claw_inv);

  for (int b = 0; b < NB; ++b) {
    const float* vis_b  = vis  + (long long)b * SD;
    const float* lang_b = lang + (long long)b * SD;
    float* out_b = out + (long long)b * SD;

    gemm_kernel<float, float, false, false, float>
        <<<dim3(D / BN, S / BM, 1), blk, 0, stream>>>(
        vis_b, vW, vb, nullptr, y, D, D, D, D, 0, 0, 0);
    ln_relu_kernel<__hip_bfloat16><<<S, blk, 0, stream>>>(
        y, vg, vbeta, (__hip_bfloat16*)vp);

    gemm_kernel<float, float, false, false, float>
        <<<dim3(D / BN, S / BM, 1), blk, 0, stream>>>(
        lang_b, lW, lb, nullptr, y, D, D, D, D, 0, 0, 0);
    ln_relu_kernel<__hip_bfloat16><<<S, blk, 0, stream>>>(
        y, lg, lbeta, (__hip_bfloat16*)lp);

    gemm_kernel<u16, u16, false, true, __hip_bfloat16>
        <<<dim3(S / BN, S / BM, 1), blk, 0, stream>>>(
        vp, lp, nullptr, scale, (__hip_bfloat16*)sim, D, D, D, S, 0, 0, 0);
    softmax_kernel<<<S, blk, 0, stream>>>(sim);

    gemm_kernel<u16, u16, false, false, __hip_bfloat16>
        <<<dim3(D / BN, S / BM, 1), blk, 0, stream>>>(
        sim, vp, nullptr, nullptr, (__hip_bfloat16*)comb, S, S, D, 2 * D, 0, 0, 0);
    gemm_kernel<u16, u16, true, false, __hip_bfloat16>
        <<<dim3(D / BN, S / BM, 1), blk, 0, stream>>>(
        sim, lp, nullptr, nullptr, (__hip_bfloat16*)comb + D, S, S, D, 2 * D, 0, 0, 0);

    gemm_kernel<u16, float, false, false, float>
        <<<dim3(D / BN, S / BM, 1), blk, 0, stream>>>(
        comb, oW, ob, nullptr, y, 2 * D, 2 * D, D, D, 0, 0, 0);
    ln_relu_kernel<float><<<S, blk, 0, stream>>>(y, og, obeta, out_b);
  }
}

// Round 6
// 899.942 us; speedup vs baseline: 2.9866x; 1.5328x over previous
//
#include <hip/hip_runtime.h>
#include <hip/hip_bf16.h>

typedef short short8 __attribute__((ext_vector_type(8)));
typedef float f32x4 __attribute__((ext_vector_type(4)));
typedef unsigned short u16;

#define BM 64
#define BN 64
#define BK 32
// LDS layout: element (row, k) at row*32 + ((k>>3) ^ ((row>>3)&3))*8 + (k&7).
// XOR granule swizzle: keeps 16B-aligned b128 reads/writes, spreads the
// NN/TN scatter writes from 16-way to 4-way bank conflict (m136: 5.69x->1.58x).
static __device__ __forceinline__ int sw(int row, int g) {
  return row * 32 + ((g ^ ((row >> 3) & 3)) << 3);
}

// fp32 -> bf16 round-to-nearest-even (payload as u16)
static __device__ __forceinline__ u16 f2b(float f) {
  union { float f; unsigned u; } x; x.f = f;
  unsigned r = x.u + 0x7FFF + ((x.u >> 16) & 1);
  return (u16)(r >> 16);
}
static __device__ __forceinline__ float b2f(u16 u) {
  unsigned int x = ((unsigned int)u) << 16;
  float f; __builtin_memcpy(&f, &x, 4);
  return f;
}

// Load 8 consecutive elements as bf16 payloads.
static __device__ __forceinline__ void load8(const u16* p, u16* dst) {
  union { uint4 u; u16 h[8]; } t;
  t.u = *(const uint4*)p;
  #pragma unroll
  for (int j = 0; j < 8; ++j) dst[j] = t.h[j];
}
static __device__ __forceinline__ void load8(const float* p, u16* dst) {
  float4 a = ((const float4*)p)[0];
  float4 b = ((const float4*)p)[1];
  dst[0] = f2b(a.x); dst[1] = f2b(a.y); dst[2] = f2b(a.z); dst[3] = f2b(a.w);
  dst[4] = f2b(b.x); dst[5] = f2b(b.y); dst[6] = f2b(b.z); dst[7] = f2b(b.w);
}

// ---------------------------------------------------------------------------
// Mixed-dtype batched GEMM: C[z] = (A[z] @ B[z]) * alpha + bias
//  TyA/TyB: float (converted at staging) or u16 (bf16 payload)
//  TA: A stored [K][M] (row stride lda); TB: B stored [N][K] (row stride ldb)
//  grid: (N/BN, M/BM, batch); block: 256 threads (4 waves)
// MFMA 16x16x32 bf16 verified layouts (guide §3, m89/m91):
//   A-frag: lane holds A[m=lane&15][k=(lane>>4)*8+j]
//   B-frag: lane holds B[k=(lane>>4)*8+j][n=lane&15]
//   C/D   : lane reg r holds D[row=(lane>>4)*4+r][col=lane&15]
// ---------------------------------------------------------------------------
template<typename TyA, typename TyB, bool TA, bool TB, typename OutT>
__global__ __launch_bounds__(256) void gemm_kernel(
    const TyA* __restrict__ A, const TyB* __restrict__ B,
    const float* __restrict__ bias, const float* __restrict__ alpha_ptr,
    OutT* __restrict__ C, int K, int lda, int ldb, int ldc,
    long long sA, long long sB, long long sC)
{
  __shared__ u16 As[BM * 32];  // swizzled [m][k]
  __shared__ u16 Bs[BN * 32];  // swizzled [n][k]

  A += (long long)blockIdx.z * sA;
  B += (long long)blockIdx.z * sB;
  C += (long long)blockIdx.z * sC;

  const int tid = threadIdx.x;
  const int m0 = blockIdx.y * BM;
  const int n0 = blockIdx.x * BN;
  const int w    = tid >> 6;     // wave 0..3 -> m rows [w*16, w*16+16)
  const int lane = tid & 63;
  const int lrow = lane & 15;
  const int lg   = lane >> 4;    // k-granule index 0..3

  // Per-lane fragment read offsets are k0-invariant: precompute.
  const int a_off = sw(w * 16 + lrow, lg);
  int b_off[4];
  #pragma unroll
  for (int i = 0; i < 4; ++i) b_off[i] = sw(i * 16 + lrow, lg);

  f32x4 acc[4] = {};

  for (int k0 = 0; k0 < K; k0 += BK) {
    union { uint4 u; u16 h[8]; } t;
    if (!TA) {  // A row-major [M][K]: vectorized b128 store, granule-relocated
      const int r = tid >> 2, g = tid & 3;
      load8(A + (long long)(m0 + r) * lda + (k0 + g * 8), t.h);
      *(uint4*)(As + sw(r, g)) = t.u;
    } else {    // A stored [K][M]: 8 scalar stores, 4-way conflict max
      const int kk = tid >> 3, mm = (tid & 7) * 8;
      load8(A + (long long)(k0 + kk) * lda + (m0 + mm), t.h);
      #pragma unroll
      for (int j = 0; j < 8; ++j) As[sw(mm + j, kk >> 3) + (kk & 7)] = t.h[j];
    }
    if (!TB) {  // B row-major [K][N]: 8 scalar stores, 4-way conflict max
      const int kk = tid >> 3, nn = (tid & 7) * 8;
      load8(B + (long long)(k0 + kk) * ldb + (n0 + nn), t.h);
      #pragma unroll
      for (int j = 0; j < 8; ++j) Bs[sw(nn + j, kk >> 3) + (kk & 7)] = t.h[j];
    } else {    // B stored [N][K]: vectorized b128 store
      const int r = tid >> 2, g = tid & 3;
      load8(B + (long long)(n0 + r) * ldb + (k0 + g * 8), t.h);
      *(uint4*)(Bs + sw(r, g)) = t.u;
    }
    __syncthreads();

    short8 a = *(const short8*)(As + a_off);
    #pragma unroll
    for (int i = 0; i < 4; ++i) {
      short8 b = *(const short8*)(Bs + b_off[i]);
      acc[i] = __builtin_amdgcn_mfma_f32_16x16x32_bf16(a, b, acc[i], 0, 0, 0);
    }
    __syncthreads();
  }

  const float alpha = alpha_ptr ? *alpha_ptr : 1.0f;
  #pragma unroll
  for (int i = 0; i < 4; ++i) {
    const int n = n0 + i * 16 + lrow;
    const float bv = bias ? bias[n] : 0.0f;
    #pragma unroll
    for (int r = 0; r < 4; ++r) {
      const int m = m0 + w * 16 + (lane >> 4) * 4 + r;
      C[(long long)m * ldc + n] = OutT(acc[i][r] * alpha + bv);
    }
  }
}

// ---------------------------------------------------------------------------
// LayerNorm + ReLU over rows of 768 fp32 -> OutT. ReLU propagates NaN.
// ---------------------------------------------------------------------------
template<typename OutT>
__global__ __launch_bounds__(256) void ln_relu_kernel(
    const float* __restrict__ x, const float* __restrict__ g,
    const float* __restrict__ beta, OutT* __restrict__ out)
{
  __shared__ float sa[4], sb[4];
  const float* xr = x + (long long)blockIdx.x * 768;
  float v[3]; float s = 0.f, ss = 0.f;
  #pragma unroll
  for (int j = 0; j < 3; ++j) {
    v[j] = xr[threadIdx.x + j * 256];
    s += v[j]; ss += v[j] * v[j];
  }
  #pragma unroll
  for (int off = 32; off; off >>= 1) {
    s  += __shfl_down(s, off);
    ss += __shfl_down(ss, off);
  }
  const int w = threadIdx.x >> 6, lane = threadIdx.x & 63;
  if (!lane) { sa[w] = s; sb[w] = ss; }
  __syncthreads();
  s  = sa[0] + sa[1] + sa[2] + sa[3];
  ss = sb[0] + sb[1] + sb[2] + sb[3];
  const float mean = s * (1.f / 768.f);
  const float var  = ss * (1.f / 768.f) - mean * mean;
  const float rst  = rsqrtf(var + 1e-5f);
  OutT* orow = out + (long long)blockIdx.x * 768;
  #pragma unroll
  for (int j = 0; j < 3; ++j) {
    const int idx = threadIdx.x + j * 256;
    const float yv = (v[j] - mean) * rst * g[idx] + beta[idx];
    const float rv = (yv <= 0.f) ? 0.f : yv;  // NaN -> yv (propagates)
    orow[idx] = OutT(rv);
  }
}

// ---------------------------------------------------------------------------
// In-place row softmax over 2048 bf16 values (fp32 math)
// ---------------------------------------------------------------------------
__global__ __launch_bounds__(256) void softmax_kernel(u16* __restrict__ sim)
{
  __shared__ float sm[4], ssum[4];
  u16* row = sim + (long long)blockIdx.x * 2048;
  union { uint4 u; u16 h[8]; } v;
  v.u = *(const uint4*)(row + threadIdx.x * 8);
  float f[8]; float mx = -1e30f;
  #pragma unroll
  for (int j = 0; j < 8; ++j) { f[j] = b2f(v.h[j]); mx = fmaxf(mx, f[j]); }
  #pragma unroll
  for (int off = 32; off; off >>= 1) mx = fmaxf(mx, __shfl_down(mx, off));
  const int w = threadIdx.x >> 6, lane = threadIdx.x & 63;
  if (!lane) sm[w] = mx;
  __syncthreads();
  mx = fmaxf(fmaxf(sm[0], sm[1]), fmaxf(sm[2], sm[3]));
  float s = 0.f;
  #pragma unroll
  for (int j = 0; j < 8; ++j) { f[j] = __expf(f[j] - mx); s += f[j]; }
  #pragma unroll
  for (int off = 32; off; off >>= 1) s += __shfl_down(s, off);
  if (!lane) ssum[w] = s;
  __syncthreads();
  s = ssum[0] + ssum[1] + ssum[2] + ssum[3];
  const float inv = 1.f / s;
  #pragma unroll
  for (int j = 0; j < 8; ++j) v.h[j] = f2b(f[j] * inv);
  *(uint4*)(row + threadIdx.x * 8) = v.u;
}

// ---------------------------------------------------------------------------
// claw mean: stage 1 — 64 blocks write partial sums (deterministic)
// ---------------------------------------------------------------------------
__global__ __launch_bounds__(256) void claw_partial_kernel(
    const float* __restrict__ claw, float* __restrict__ partial, int n)
{
  __shared__ float sa[4];
  float s = 0.f;
  const int nv = n >> 2;
  for (int i = blockIdx.x * 256 + threadIdx.x; i < nv; i += 64 * 256) {
    float4 v = ((const float4*)claw)[i];
    s += v.x + v.y + v.z + v.w;
  }
  #pragma unroll
  for (int off = 32; off; off >>= 1) s += __shfl_down(s, off);
  const int w = threadIdx.x >> 6, lane = threadIdx.x & 63;
  if (!lane) sa[w] = s;
  __syncthreads();
  if (threadIdx.x == 0)
    partial[blockIdx.x] = sa[0] + sa[1] + sa[2] + sa[3];
}

// stage 2 — 1 block of 64 lanes: scale = (sum partial)/(n*T)
__global__ void claw_final_kernel(
    const float* __restrict__ partial, float* __restrict__ scale, float inv)
{
  float s = partial[threadIdx.x];
  #pragma unroll
  for (int off = 32; off; off >>= 1) s += __shfl_down(s, off);
  if (threadIdx.x == 0) *scale = s * inv;
}

// ---------------------------------------------------------------------------
extern "C" void kernel_launch(void* const* d_in, const int* in_sizes, int n_in,
                              void* d_out, int out_size, void* d_ws, size_t ws_size,
                              hipStream_t stream)
{
  // Reference setup_inputs(): ALL tensors float32; reference OUTPUT is float32.
  const float* vis   = (const float*)d_in[0];
  const float* lang  = (const float*)d_in[1];
  const float* vW    = (const float*)d_in[2];
  const float* vb    = (const float*)d_in[3];
  const float* vg    = (const float*)d_in[4];
  const float* vbeta = (const float*)d_in[5];
  const float* lW    = (const float*)d_in[6];
  const float* lb    = (const float*)d_in[7];
  const float* lg    = (const float*)d_in[8];
  const float* lbeta = (const float*)d_in[9];
  const float* claw  = (const float*)d_in[10];
  const float* oW    = (const float*)d_in[11];
  const float* ob    = (const float*)d_in[12];
  const float* og    = (const float*)d_in[13];
  const float* obeta = (const float*)d_in[14];
  float* out = (float*)d_out;

  constexpr int NB = 8, S = 2048, D = 768;
  constexpr long long SD = (long long)S * D;      // 1,572,864
  constexpr long long SS = (long long)S * S;      // 4,194,304
  const int nclaw = in_sizes[10];
  const float claw_inv = 1.0f / ((float)nclaw * 0.07f);
  const dim3 blk(256);

  // ---- full-batch workspace layout (167,772,432 B) ----
  const size_t need_full = 167772432;

  char* ws = (char*)d_ws;
  if (ws_size >= need_full) {
    constexpr int R = NB * S;  // 16384
    u16*   vp      = (u16*)  (ws);
    u16*   lp      = (u16*)  (ws + 25165824);
    u16*   comb    = (u16*)  (ws + 50331648);
    u16*   sim     = (u16*)  (ws + 100663296);
    float* y       = (float*)(ws + 100663296);  // aliases sim (disjoint lifetimes)
    float* scale   = (float*)(ws + 167772160);
    float* partial = (float*)(ws + 167772176);

    claw_partial_kernel<<<64, blk, 0, stream>>>(claw, partial, nclaw);
    claw_final_kernel<<<1, 64, 0, stream>>>(partial, scale, claw_inv);

    // vision projection over all 16384 rows
    gemm_kernel<float, float, false, false, float>
        <<<dim3(D / BN, R / BM, 1), blk, 0, stream>>>(
        vis, vW, vb, nullptr, y, D, D, D, D, 0, 0, 0);
    ln_relu_kernel<__hip_bfloat16><<<R, blk, 0, stream>>>(
        y, vg, vbeta, (__hip_bfloat16*)vp);

    // language projection
    gemm_kernel<float, float, false, false, float>
        <<<dim3(D / BN, R / BM, 1), blk, 0, stream>>>(
        lang, lW, lb, nullptr, y, D, D, D, D, 0, 0, 0);
    ln_relu_kernel<__hip_bfloat16><<<R, blk, 0, stream>>>(
        y, lg, lbeta, (__hip_bfloat16*)lp);

    // sim[z] = (vp[z] @ lp[z]^T) * scale ; softmax rows in place
    gemm_kernel<u16, u16, false, true, __hip_bfloat16>
        <<<dim3(S / BN, S / BM, NB), blk, 0, stream>>>(
        vp, lp, nullptr, scale, (__hip_bfloat16*)sim, D, D, D, S, SD, SD, SS);
    softmax_kernel<<<R, blk, 0, stream>>>(sim);

    // aligned_vision[z] = A[z] @ vp[z] -> comb[:, 0:768]
    gemm_kernel<u16, u16, false, false, __hip_bfloat16>
        <<<dim3(D / BN, S / BM, NB), blk, 0, stream>>>(
        sim, vp, nullptr, nullptr, (__hip_bfloat16*)comb,
        S, S, D, 2 * D, SS, SD, 2 * SD);
    // aligned_language[z] = A[z]^T @ lp[z] -> comb[:, 768:1536]
    gemm_kernel<u16, u16, true, false, __hip_bfloat16>
        <<<dim3(D / BN, S / BM, NB), blk, 0, stream>>>(
        sim, lp, nullptr, nullptr, (__hip_bfloat16*)comb + D,
        S, S, D, 2 * D, SS, SD, 2 * SD);

    // out = relu(LN(comb @ oW + ob))   (final GEMM writes y over dead sim)
    gemm_kernel<u16, float, false, false, float>
        <<<dim3(D / BN, R / BM, 1), blk, 0, stream>>>(
        comb, oW, ob, nullptr, y, 2 * D, 2 * D, D, D, 0, 0, 0);
    ln_relu_kernel<float><<<R, blk, 0, stream>>>(y, og, obeta, out);
    return;
  }

  // ---- fallback: per-batch loop, 27.3 MB workspace (round-4 proven path) ----
  u16*   vp      = (u16*)  (ws);
  u16*   lp      = (u16*)  (ws +  3145728);
  u16*   comb    = (u16*)  (ws +  6291456);
  u16*   sim     = (u16*)  (ws + 12582912);
  float* y       = (float*)(ws + 20971520);
  float* scale   = (float*)(ws + 27262976);
  float* partial = (float*)(ws + 27262992);

  claw_partial_kernel<<<64, blk, 0, stream>>>(claw, partial, nclaw);
  claw_final_kernel<<<1, 64, 0, stream>>>(partial, scale, claw_inv);

  for (int b = 0; b < NB; ++b) {
    const float* vis_b  = vis  + (long long)b * SD;
    const float* lang_b = lang + (long long)b * SD;
    float* out_b = out + (long long)b * SD;

    gemm_kernel<float, float, false, false, float>
        <<<dim3(D / BN, S / BM, 1), blk, 0, stream>>>(
        vis_b, vW, vb, nullptr, y, D, D, D, D, 0, 0, 0);
    ln_relu_kernel<__hip_bfloat16><<<S, blk, 0, stream>>>(
        y, vg, vbeta, (__hip_bfloat16*)vp);

    gemm_kernel<float, float, false, false, float>
        <<<dim3(D / BN, S / BM, 1), blk, 0, stream>>>(
        lang_b, lW, lb, nullptr, y, D, D, D, D, 0, 0, 0);
    ln_relu_kernel<__hip_bfloat16><<<S, blk, 0, stream>>>(
        y, lg, lbeta, (__hip_bfloat16*)lp);

    gemm_kernel<u16, u16, false, true, __hip_bfloat16>
        <<<dim3(S / BN, S / BM, 1), blk, 0, stream>>>(
        vp, lp, nullptr, scale, (__hip_bfloat16*)sim, D, D, D, S, 0, 0, 0);
    softmax_kernel<<<S, blk, 0, stream>>>(sim);

    gemm_kernel<u16, u16, false, false, __hip_bfloat16>
        <<<dim3(D / BN, S / BM, 1), blk, 0, stream>>>(
        sim, vp, nullptr, nullptr, (__hip_bfloat16*)comb, S, S, D, 2 * D, 0, 0, 0);
    gemm_kernel<u16, u16, true, false, __hip_bfloat16>
        <<<dim3(D / BN, S / BM, 1), blk, 0, stream>>>(
        sim, lp, nullptr, nullptr, (__hip_bfloat16*)comb + D, S, S, D, 2 * D, 0, 0, 0);

    gemm_kernel<u16, float, false, false, float>
        <<<dim3(D / BN, S / BM, 1), blk, 0, stream>>>(
        comb, oW, ob, nullptr, y, 2 * D, 2 * D, D, D, 0, 0, 0);
    ln_relu_kernel<float><<<S, blk, 0, stream>>>(y, og, obeta, out_b);
  }
}

// Round 7
// 675.093 us; speedup vs baseline: 3.9813x; 1.3331x over previous
//
#include <hip/hip_runtime.h>
#include <hip/hip_bf16.h>

typedef short short8 __attribute__((ext_vector_type(8)));
typedef float f32x4 __attribute__((ext_vector_type(4)));
typedef unsigned short u16;

#define BK 32
// Swizzled LDS layout for scatter-staged operands:
// element (row,k) at row*32 + ((k>>3) ^ ((row>>3)&3))*8 + (k&7); caps scatter
// write conflicts at 4-way (proven round 6: 1.92e8 -> 4.09e7 conflict cycles).
static __device__ __forceinline__ int sw(int row, int g) {
  return row * 32 + ((g ^ ((row >> 3) & 3)) << 3);
}

// fp32 -> bf16 round-to-nearest-even (payload as u16)
static __device__ __forceinline__ u16 f2b(float f) {
  union { float f; unsigned u; } x; x.f = f;
  unsigned r = x.u + 0x7FFF + ((x.u >> 16) & 1);
  return (u16)(r >> 16);
}
static __device__ __forceinline__ float b2f(u16 u) {
  unsigned int x = ((unsigned int)u) << 16;
  float f; __builtin_memcpy(&f, &x, 4);
  return f;
}

// Load 8 consecutive elements as bf16 payloads.
static __device__ __forceinline__ void load8(const u16* p, u16* dst) {
  union { uint4 u; u16 h[8]; } t;
  t.u = *(const uint4*)p;
  #pragma unroll
  for (int j = 0; j < 8; ++j) dst[j] = t.h[j];
}
static __device__ __forceinline__ void load8(const float* p, u16* dst) {
  float4 a = ((const float4*)p)[0];
  float4 b = ((const float4*)p)[1];
  dst[0] = f2b(a.x); dst[1] = f2b(a.y); dst[2] = f2b(a.z); dst[3] = f2b(a.w);
  dst[4] = f2b(b.x); dst[5] = f2b(b.y); dst[6] = f2b(b.z); dst[7] = f2b(b.w);
}

// Async global->LDS, 16B per lane (gfx950 global_load_lds_dwordx4).
// LDS dest must be wave-uniform base + lane*16 (m104/m108 caveat).
static __device__ __forceinline__ void gl_lds16(const u16* g, u16* l) {
  __builtin_amdgcn_global_load_lds(
      (const __attribute__((address_space(1))) unsigned int*)g,
      (__attribute__((address_space(3))) unsigned int*)l, 16, 0, 0);
}

// ---------------------------------------------------------------------------
// 128x128x32 MFMA GEMM (m97 structure): C[z] = (A[z] @ B[z]) * alpha + bias
// Staging modes per operand:
//   0 DIRECT : bf16, k-contiguous rows (A:[M][K], B:[N][K]); global_load_lds.
//   1 SCATTER: k-strided ([K][M] / [K][N]), u16 or float; swizzled scatter.
//   2 CONVERT: fp32 row-major [M][K]; vector load + cvt + b128 store. (A only)
// 4 waves (2x2), each computes 64x64 = 4x4 MFMAs of 16x16x32.
// Verified fragment maps (m89/m91): A: m=lane&15,k=(lane>>4)*8+j;
// B: n=lane&15; C/D: row=(lane>>4)*4+r, col=lane&15.
// ---------------------------------------------------------------------------
template<int MA, int MB, typename TyA, typename TyB, typename OutT>
__global__ __launch_bounds__(256) void gemm128(
    const TyA* __restrict__ A, const TyB* __restrict__ B,
    const float* __restrict__ bias, const float* __restrict__ alpha_ptr,
    OutT* __restrict__ C, int K, int lda, int ldb, int ldc,
    long long sA, long long sB, long long sC)
{
  __shared__ u16 As[128 * 32];  // 8 KB
  __shared__ u16 Bs[128 * 32];  // 8 KB

  A += (long long)blockIdx.z * sA;
  B += (long long)blockIdx.z * sB;
  C += (long long)blockIdx.z * sC;

  const int tid  = threadIdx.x;
  const int m0   = blockIdx.y * 128;
  const int n0   = blockIdx.x * 128;
  const int w    = tid >> 6, lane = tid & 63;
  const int wm   = (w >> 1) * 64;   // wave row origin in tile
  const int wn   = (w & 1) * 64;    // wave col origin in tile
  const int lrow = lane & 15;
  const int lg   = lane >> 4;       // k-granule 0..3

  // k0-invariant fragment read offsets (mode-dependent layout)
  int aoff[4], boff[4];
  #pragma unroll
  for (int t = 0; t < 4; ++t) {
    const int ar = wm + t * 16 + lrow;
    const int br = wn + t * 16 + lrow;
    aoff[t] = (MA == 1) ? sw(ar, lg) : ar * 32 + lg * 8;
    boff[t] = (MB == 1) ? sw(br, lg) : br * 32 + lg * 8;
  }

  f32x4 acc[4][4] = {};

  for (int k0 = 0; k0 < K; k0 += BK) {
    // ---- stage A tile (128 x 32) ----
    if constexpr (MA == 0) {
      gl_lds16(A + (long long)(m0 + (tid >> 2)) * lda + (k0 + (tid & 3) * 8),
               As + tid * 8);
      gl_lds16(A + (long long)(m0 + 64 + (tid >> 2)) * lda + (k0 + (tid & 3) * 8),
               As + 2048 + tid * 8);
    } else if constexpr (MA == 1) {
      const int kk = tid >> 3;
      #pragma unroll
      for (int p = 0; p < 2; ++p) {
        const int rr = (tid & 7) * 8 + p * 64;
        u16 h[8];
        load8(A + (long long)(k0 + kk) * lda + (m0 + rr), h);
        #pragma unroll
        for (int j = 0; j < 8; ++j) As[sw(rr + j, kk >> 3) + (kk & 7)] = h[j];
      }
    } else {  // CONVERT: fp32 row-major
      const int g = tid & 3;
      #pragma unroll
      for (int p = 0; p < 2; ++p) {
        const int r = (tid >> 2) + p * 64;
        union { uint4 u; u16 h[8]; } t;
        load8(A + (long long)(m0 + r) * lda + (k0 + g * 8), t.h);
        *(uint4*)(As + r * 32 + g * 8) = t.u;
      }
    }
    // ---- stage B tile (128 x 32) ----
    if constexpr (MB == 0) {
      gl_lds16(B + (long long)(n0 + (tid >> 2)) * ldb + (k0 + (tid & 3) * 8),
               Bs + tid * 8);
      gl_lds16(B + (long long)(n0 + 64 + (tid >> 2)) * ldb + (k0 + (tid & 3) * 8),
               Bs + 2048 + tid * 8);
    } else {
      const int kk = tid >> 3;
      #pragma unroll
      for (int p = 0; p < 2; ++p) {
        const int rr = (tid & 7) * 8 + p * 64;
        u16 h[8];
        load8(B + (long long)(k0 + kk) * ldb + (n0 + rr), h);
        #pragma unroll
        for (int j = 0; j < 8; ++j) Bs[sw(rr + j, kk >> 3) + (kk & 7)] = h[j];
      }
    }
    __syncthreads();

    short8 af[4], bf[4];
    #pragma unroll
    for (int t = 0; t < 4; ++t) af[t] = *(const short8*)(As + aoff[t]);
    #pragma unroll
    for (int t = 0; t < 4; ++t) bf[t] = *(const short8*)(Bs + boff[t]);
    #pragma unroll
    for (int mt = 0; mt < 4; ++mt)
      #pragma unroll
      for (int nt = 0; nt < 4; ++nt)
        acc[mt][nt] = __builtin_amdgcn_mfma_f32_16x16x32_bf16(
            af[mt], bf[nt], acc[mt][nt], 0, 0, 0);
    __syncthreads();
  }

  const float alpha = alpha_ptr ? *alpha_ptr : 1.0f;
  #pragma unroll
  for (int nt = 0; nt < 4; ++nt) {
    const int n = n0 + wn + nt * 16 + lrow;
    const float bv = bias ? bias[n] : 0.0f;
    #pragma unroll
    for (int mt = 0; mt < 4; ++mt) {
      #pragma unroll
      for (int r = 0; r < 4; ++r) {
        const int m = m0 + wm + mt * 16 + lg * 4 + r;
        C[(long long)m * ldc + n] = OutT(acc[mt][nt][r] * alpha + bv);
      }
    }
  }
}

// ---------------------------------------------------------------------------
// LayerNorm + ReLU over rows of 768 fp32 -> OutT. ReLU propagates NaN.
// ---------------------------------------------------------------------------
template<typename OutT>
__global__ __launch_bounds__(256) void ln_relu_kernel(
    const float* __restrict__ x, const float* __restrict__ g,
    const float* __restrict__ beta, OutT* __restrict__ out)
{
  __shared__ float sa[4], sb[4];
  const float* xr = x + (long long)blockIdx.x * 768;
  float v[3]; float s = 0.f, ss = 0.f;
  #pragma unroll
  for (int j = 0; j < 3; ++j) {
    v[j] = xr[threadIdx.x + j * 256];
    s += v[j]; ss += v[j] * v[j];
  }
  #pragma unroll
  for (int off = 32; off; off >>= 1) {
    s  += __shfl_down(s, off);
    ss += __shfl_down(ss, off);
  }
  const int w = threadIdx.x >> 6, lane = threadIdx.x & 63;
  if (!lane) { sa[w] = s; sb[w] = ss; }
  __syncthreads();
  s  = sa[0] + sa[1] + sa[2] + sa[3];
  ss = sb[0] + sb[1] + sb[2] + sb[3];
  const float mean = s * (1.f / 768.f);
  const float var  = ss * (1.f / 768.f) - mean * mean;
  const float rst  = rsqrtf(var + 1e-5f);
  OutT* orow = out + (long long)blockIdx.x * 768;
  #pragma unroll
  for (int j = 0; j < 3; ++j) {
    const int idx = threadIdx.x + j * 256;
    const float yv = (v[j] - mean) * rst * g[idx] + beta[idx];
    const float rv = (yv <= 0.f) ? 0.f : yv;  // NaN -> yv (propagates)
    orow[idx] = OutT(rv);
  }
}

// ---------------------------------------------------------------------------
// In-place row softmax over 2048 bf16 values (fp32 math)
// ---------------------------------------------------------------------------
__global__ __launch_bounds__(256) void softmax_kernel(u16* __restrict__ sim)
{
  __shared__ float sm[4], ssum[4];
  u16* row = sim + (long long)blockIdx.x * 2048;
  union { uint4 u; u16 h[8]; } v;
  v.u = *(const uint4*)(row + threadIdx.x * 8);
  float f[8]; float mx = -1e30f;
  #pragma unroll
  for (int j = 0; j < 8; ++j) { f[j] = b2f(v.h[j]); mx = fmaxf(mx, f[j]); }
  #pragma unroll
  for (int off = 32; off; off >>= 1) mx = fmaxf(mx, __shfl_down(mx, off));
  const int w = threadIdx.x >> 6, lane = threadIdx.x & 63;
  if (!lane) sm[w] = mx;
  __syncthreads();
  mx = fmaxf(fmaxf(sm[0], sm[1]), fmaxf(sm[2], sm[3]));
  float s = 0.f;
  #pragma unroll
  for (int j = 0; j < 8; ++j) { f[j] = __expf(f[j] - mx); s += f[j]; }
  #pragma unroll
  for (int off = 32; off; off >>= 1) s += __shfl_down(s, off);
  if (!lane) ssum[w] = s;
  __syncthreads();
  s = ssum[0] + ssum[1] + ssum[2] + ssum[3];
  const float inv = 1.f / s;
  #pragma unroll
  for (int j = 0; j < 8; ++j) v.h[j] = f2b(f[j] * inv);
  *(uint4*)(row + threadIdx.x * 8) = v.u;
}

// ---------------------------------------------------------------------------
// claw mean, two deterministic stages
// ---------------------------------------------------------------------------
__global__ __launch_bounds__(256) void claw_partial_kernel(
    const float* __restrict__ claw, float* __restrict__ partial, int n)
{
  __shared__ float sa[4];
  float s = 0.f;
  const int nv = n >> 2;
  for (int i = blockIdx.x * 256 + threadIdx.x; i < nv; i += 64 * 256) {
    float4 v = ((const float4*)claw)[i];
    s += v.x + v.y + v.z + v.w;
  }
  #pragma unroll
  for (int off = 32; off; off >>= 1) s += __shfl_down(s, off);
  const int w = threadIdx.x >> 6, lane = threadIdx.x & 63;
  if (!lane) sa[w] = s;
  __syncthreads();
  if (threadIdx.x == 0)
    partial[blockIdx.x] = sa[0] + sa[1] + sa[2] + sa[3];
}

__global__ void claw_final_kernel(
    const float* __restrict__ partial, float* __restrict__ scale, float inv)
{
  float s = partial[threadIdx.x];
  #pragma unroll
  for (int off = 32; off; off >>= 1) s += __shfl_down(s, off);
  if (threadIdx.x == 0) *scale = s * inv;
}

// ---------------------------------------------------------------------------
extern "C" void kernel_launch(void* const* d_in, const int* in_sizes, int n_in,
                              void* d_out, int out_size, void* d_ws, size_t ws_size,
                              hipStream_t stream)
{
  const float* vis   = (const float*)d_in[0];
  const float* lang  = (const float*)d_in[1];
  const float* vW    = (const float*)d_in[2];
  const float* vb    = (const float*)d_in[3];
  const float* vg    = (const float*)d_in[4];
  const float* vbeta = (const float*)d_in[5];
  const float* lW    = (const float*)d_in[6];
  const float* lb    = (const float*)d_in[7];
  const float* lg    = (const float*)d_in[8];
  const float* lbeta = (const float*)d_in[9];
  const float* claw  = (const float*)d_in[10];
  const float* oW    = (const float*)d_in[11];
  const float* ob    = (const float*)d_in[12];
  const float* og    = (const float*)d_in[13];
  const float* obeta = (const float*)d_in[14];
  float* out = (float*)d_out;

  constexpr int NB = 8, S = 2048, D = 768;
  constexpr int R = NB * S;                       // 16384
  constexpr long long SD = (long long)S * D;      // 1,572,864
  constexpr long long SS = (long long)S * S;      // 4,194,304
  const int nclaw = in_sizes[10];
  const float claw_inv = 1.0f / ((float)nclaw * 0.07f);
  const dim3 blk(256);

  // Workspace (167,772,432 B; ws_size >= this proven by rounds 5/6 running
  // the full-batch path — z=8 dispatch signatures in the profile):
  char* ws = (char*)d_ws;
  u16*   vp      = (u16*)  (ws);              // bf16 [R][768]
  u16*   lp      = (u16*)  (ws + 25165824);   // bf16 [R][768]
  u16*   comb    = (u16*)  (ws + 50331648);   // bf16 [R][1536]
  u16*   sim     = (u16*)  (ws + 100663296);  // bf16 [8][2048][2048]
  float* y       = (float*)(ws + 100663296);  // fp32 [R][768], aliases sim
  float* scale   = (float*)(ws + 167772160);
  float* partial = (float*)(ws + 167772176);

  claw_partial_kernel<<<64, blk, 0, stream>>>(claw, partial, nclaw);
  claw_final_kernel<<<1, 64, 0, stream>>>(partial, scale, claw_inv);

  // vision projection: y = vis @ vW + vb ; vp = relu(LN(y))
  gemm128<2, 1, float, float, float>
      <<<dim3(D / 128, R / 128, 1), blk, 0, stream>>>(
      vis, vW, vb, nullptr, y, D, D, D, D, 0, 0, 0);
  ln_relu_kernel<__hip_bfloat16><<<R, blk, 0, stream>>>(
      y, vg, vbeta, (__hip_bfloat16*)vp);

  // language projection
  gemm128<2, 1, float, float, float>
      <<<dim3(D / 128, R / 128, 1), blk, 0, stream>>>(
      lang, lW, lb, nullptr, y, D, D, D, D, 0, 0, 0);
  ln_relu_kernel<__hip_bfloat16><<<R, blk, 0, stream>>>(
      y, lg, lbeta, (__hip_bfloat16*)lp);

  // sim[z] = (vp[z] @ lp[z]^T) * scale   (both operands DIRECT)
  gemm128<0, 0, u16, u16, __hip_bfloat16>
      <<<dim3(S / 128, S / 128, NB), blk, 0, stream>>>(
      vp, lp, nullptr, scale, (__hip_bfloat16*)sim, D, D, D, S, SD, SD, SS);
  softmax_kernel<<<R, blk, 0, stream>>>(sim);

  // aligned_vision[z] = A[z] @ vp[z] -> comb[:, 0:768]  (A direct, B scatter)
  gemm128<0, 1, u16, u16, __hip_bfloat16>
      <<<dim3(D / 128, S / 128, NB), blk, 0, stream>>>(
      sim, vp, nullptr, nullptr, (__hip_bfloat16*)comb,
      S, S, D, 2 * D, SS, SD, 2 * SD);
  // aligned_language[z] = A[z]^T @ lp[z] -> comb[:, 768:1536] (both scatter)
  gemm128<1, 1, u16, u16, __hip_bfloat16>
      <<<dim3(D / 128, S / 128, NB), blk, 0, stream>>>(
      sim, lp, nullptr, nullptr, (__hip_bfloat16*)comb + D,
      S, S, D, 2 * D, SS, SD, 2 * SD);

  // out = relu(LN(comb @ oW + ob))   (A direct, B scatter; y over dead sim)
  gemm128<0, 1, u16, float, float>
      <<<dim3(D / 128, R / 128, 1), blk, 0, stream>>>(
      comb, oW, ob, nullptr, y, 2 * D, 2 * D, D, D, 0, 0, 0);
  ln_relu_kernel<float><<<R, blk, 0, stream>>>(y, og, obeta, out);
}